// Round 3
// baseline (1064.652 us; speedup 1.0000x reference)
//
#include <hip/hip_runtime.h>
#include <math.h>

#define B_ 4
#define N_ 50000
#define E_ 800000
#define IN_ 128
#define H_ 4
#define D_ 32
#define HD_ 128
#define M_ (B_*N_)   // 200000 rows total

constexpr float GAT_SLOPE = 0.2f;
constexpr float ACT_SLOPE = 0.01f;
constexpr float BN_EPS = 1e-5f;

__device__ __forceinline__ unsigned short f2bf(float x) {
    unsigned u = __float_as_uint(x);
    unsigned r = (u + 0x7FFFu + ((u >> 16) & 1u)) >> 16;
    return (unsigned short)r;
}
__device__ __forceinline__ float bf2f(unsigned short h) {
    return __uint_as_float(((unsigned)h) << 16);
}

// ---- GEMM: feat_bf16[row, c] = sum_k xx[row,k] * W[k,c]  (rows=B*N, K=C=128) ----
__global__ __launch_bounds__(256) void gemm_kernel(const float* __restrict__ xx,
                                                   const float* __restrict__ W,
                                                   unsigned short* __restrict__ featb) {
    __shared__ float Ws[IN_ * HD_];   // 64 KB, [k][c]
    __shared__ float Xt[IN_][64];     // 32 KB, transposed [k][r]
    const int tid = threadIdx.x;
    const long row0 = (long)blockIdx.x * 64;

    for (int i = tid; i < IN_ * HD_ / 4; i += 256)
        ((float4*)Ws)[i] = ((const float4*)W)[i];
    for (int i = tid; i < 64 * IN_ / 4; i += 256) {
        int r = i >> 5;            // 32 float4 per row
        int k4 = (i & 31) << 2;
        float4 v = ((const float4*)(xx + (row0 + r) * IN_))[i & 31];
        Xt[k4 + 0][r] = v.x; Xt[k4 + 1][r] = v.y;
        Xt[k4 + 2][r] = v.z; Xt[k4 + 3][r] = v.w;
    }
    __syncthreads();

    const int cl = tid & 31;         // cols 4*cl .. 4*cl+3 (consecutive)
    const int r0 = (tid >> 5) * 8;   // 8 rows per thread
    float acc[8][4] = {};
    for (int k = 0; k < IN_; ++k) {
        float4 wv = *(const float4*)&Ws[k * HD_ + 4 * cl];
        float4 xa = *(const float4*)&Xt[k][r0];
        float4 xb = *(const float4*)&Xt[k][r0 + 4];
        float xr[8] = {xa.x, xa.y, xa.z, xa.w, xb.x, xb.y, xb.z, xb.w};
#pragma unroll
        for (int i = 0; i < 8; ++i) {
            acc[i][0] = fmaf(xr[i], wv.x, acc[i][0]);
            acc[i][1] = fmaf(xr[i], wv.y, acc[i][1]);
            acc[i][2] = fmaf(xr[i], wv.z, acc[i][2]);
            acc[i][3] = fmaf(xr[i], wv.w, acc[i][3]);
        }
    }
#pragma unroll
    for (int i = 0; i < 8; ++i) {
        long r = row0 + r0 + i;
        ushort4 pv;
        pv.x = f2bf(acc[i][0]); pv.y = f2bf(acc[i][1]);
        pv.z = f2bf(acc[i][2]); pv.w = f2bf(acc[i][3]);
        *(ushort4*)&featb[r * HD_ + 4 * cl] = pv;
    }
}

// ---- el/er: per-node per-head dot of feat with attn vectors ----
__global__ __launch_bounds__(256) void elr_kernel(const unsigned short* __restrict__ featb,
                                                  const float* __restrict__ al,
                                                  const float* __restrict__ ar,
                                                  float* __restrict__ el,
                                                  float* __restrict__ er) {
    const int tid = threadIdx.x;
    const int c = tid & 127;
    const int h = c >> 5, d = c & 31;
    const int half = tid >> 7;
    for (long rp = blockIdx.x; rp < M_ / 2; rp += gridDim.x) {
        long row = rp * 2 + half;
        float f = bf2f(featb[row * HD_ + c]);
        float pl = f * al[c];
        float pr = f * ar[c];
        for (int o = 16; o; o >>= 1) {
            pl += __shfl_down(pl, o, 32);
            pr += __shfl_down(pr, o, 32);
        }
        if (d == 0) {
            el[row * H_ + h] = pl;
            er[row * H_ + h] = pr;
        }
    }
}

// ---- CSR build step 1: in-degree histogram over dst ----
__global__ __launch_bounds__(256) void hist_kernel(const int* __restrict__ dst,
                                                   int* __restrict__ counts) {
    for (int e = blockIdx.x * 256 + threadIdx.x; e < E_; e += gridDim.x * 256)
        atomicAdd(&counts[dst[e]], 1);
}

// ---- CSR build step 2: exclusive scan of counts -> offsets (+cursor copy) ----
__global__ __launch_bounds__(1024) void scan_kernel(const int* __restrict__ counts,
                                                    int* __restrict__ offsets,
                                                    int* __restrict__ cursor) {
    __shared__ int part[1024];
    const int tid = threadIdx.x;
    const int CH = (N_ + 1023) / 1024;   // 49
    const int base = tid * CH;
    int s = 0;
    for (int i = 0; i < CH; ++i) {
        int idx = base + i;
        if (idx < N_) s += counts[idx];
    }
    part[tid] = s;
    __syncthreads();
    for (int off = 1; off < 1024; off <<= 1) {
        int v = (tid >= off) ? part[tid - off] : 0;
        __syncthreads();
        part[tid] += v;
        __syncthreads();
    }
    int run = (tid == 0) ? 0 : part[tid - 1];
    for (int i = 0; i < CH; ++i) {
        int idx = base + i;
        if (idx < N_) {
            offsets[idx] = run;
            cursor[idx] = run;
            run += counts[idx];
        }
    }
    if (tid == 0) offsets[N_] = part[1023];   // == E_
}

// ---- CSR build step 3: scatter src ids into dst-sorted order ----
__global__ __launch_bounds__(256) void scatter_kernel(const int* __restrict__ src,
                                                      const int* __restrict__ dst,
                                                      int* __restrict__ cursor,
                                                      int* __restrict__ srcs) {
    for (int e = blockIdx.x * 256 + threadIdx.x; e < E_; e += gridDim.x * 256) {
        int pos = atomicAdd(&cursor[dst[e]], 1);
        srcs[pos] = src[e];
    }
}

// ---- per-(b,node) softmax + aggregation ----
// No max subtraction: scores are O(±6), exp can't overflow f32, and alpha is
// shift-invariant. One exp per (edge,head) in its owner lane; w/src broadcast
// to the 32-lane head group via shfl.
__global__ __launch_bounds__(128) void aggregate_kernel(const int* __restrict__ offsets,
                                                        const int* __restrict__ srcs,
                                                        const float* __restrict__ el,
                                                        const float* __restrict__ er,
                                                        const unsigned short* __restrict__ featb,
                                                        float* __restrict__ out) {
    const int t = threadIdx.x;       // channel 0..127
    const int h = t >> 5;            // head
    const int lane = t & 31;
    const long bn = blockIdx.x;      // b*N + n
    const int b = (int)(bn / N_);
    const int n = (int)(bn % N_);
    const long bbase = (long)b * N_;
    const int beg = offsets[n], end = offsets[n + 1];

    const float ern = er[(bbase + n) * H_ + h];

    float acc = 0.f, denom = 0.f;
    for (int c0 = beg; c0 < end; c0 += 32) {
        const int i = c0 + lane;
        int s = 0;
        float w = 0.f;
        if (i < end) {
            s = srcs[i];
            float ev = el[(bbase + s) * H_ + h] + ern;
            ev = ev >= 0.f ? ev : GAT_SLOPE * ev;
            w = __expf(ev);
        }
        denom += w;
        const int cnt = min(32, end - c0);
        for (int j = 0; j < cnt; ++j) {
            float wj = __shfl(w, j, 32);
            int sj = __shfl(s, j, 32);
            float f = bf2f(featb[(bbase + sj) * HD_ + t]);
            acc = fmaf(wj, f, acc);
        }
    }
#pragma unroll
    for (int o = 16; o; o >>= 1) denom += __shfl_xor(denom, o, 32);
    out[bn * HD_ + t] = acc / fmaxf(denom, 1e-9f);
}

// ---- per-channel sum/sumsq for BN (read-only) ----
__global__ __launch_bounds__(256) void stats_kernel(const float* __restrict__ out,
                                                    float* __restrict__ chsum) {
    const int tid = threadIdx.x;
    const int c = tid & 127;
    const int half = tid >> 7;
    float s = 0.f, s2 = 0.f;
    for (long rp = blockIdx.x; rp < M_ / 2; rp += gridDim.x) {
        long row = rp * 2 + half;
        float v = out[row * HD_ + c];
        s += v;
        s2 += v * v;
    }
    __shared__ float red[512];
    red[tid] = s; red[256 + tid] = s2;
    __syncthreads();
    if (tid < 128) {
        s = red[tid] + red[tid + 128];
        s2 = red[256 + tid] + red[256 + tid + 128];
        atomicAdd(&chsum[c], s);
        atomicAdd(&chsum[128 + c], s2);
    }
}

// ---- BN params: scale/shift per channel ----
__global__ void params_kernel(const float* __restrict__ chsum,
                              const float* __restrict__ gamma,
                              const float* __restrict__ beta,
                              float* __restrict__ ss) {
    int c = threadIdx.x;  // 128 threads
    float mean = chsum[c] / (float)M_;
    float var = chsum[128 + c] / (float)M_ - mean * mean;
    float rstd = rsqrtf(var + BN_EPS);
    float sc = rstd * gamma[c];
    ss[c] = sc;
    ss[128 + c] = beta[c] - mean * sc;
}

// ---- normalize + final leaky relu, in place on d_out ----
__global__ __launch_bounds__(256) void norm_kernel(float* __restrict__ out,
                                                   const float* __restrict__ ss) {
    __shared__ float s_sc[128], s_sh[128];
    if (threadIdx.x < 128) {
        s_sc[threadIdx.x] = ss[threadIdx.x];
        s_sh[threadIdx.x] = ss[128 + threadIdx.x];
    }
    __syncthreads();
    const long total4 = (long)M_ * HD_ / 4;
    for (long i = (long)blockIdx.x * 256 + threadIdx.x; i < total4;
         i += (long)gridDim.x * 256) {
        float4 v = ((float4*)out)[i];
        int c = (int)((i & 31) << 2);   // (i*4) % 128
        float4 r;
        r.x = v.x * s_sc[c + 0] + s_sh[c + 0];
        r.y = v.y * s_sc[c + 1] + s_sh[c + 1];
        r.z = v.z * s_sc[c + 2] + s_sh[c + 2];
        r.w = v.w * s_sc[c + 3] + s_sh[c + 3];
        r.x = r.x >= 0.f ? r.x : ACT_SLOPE * r.x;
        r.y = r.y >= 0.f ? r.y : ACT_SLOPE * r.y;
        r.z = r.z >= 0.f ? r.z : ACT_SLOPE * r.z;
        r.w = r.w >= 0.f ? r.w : ACT_SLOPE * r.w;
        ((float4*)out)[i] = r;
    }
}

extern "C" void kernel_launch(void* const* d_in, const int* in_sizes, int n_in,
                              void* d_out, int out_size, void* d_ws, size_t ws_size,
                              hipStream_t stream) {
    const float* xx    = (const float*)d_in[0];
    const float* W     = (const float*)d_in[1];
    const float* al    = (const float*)d_in[2];
    const float* ar    = (const float*)d_in[3];
    const float* gamma = (const float*)d_in[4];
    const float* beta  = (const float*)d_in[5];
    const int*   src   = (const int*)d_in[6];
    const int*   dst   = (const int*)d_in[7];
    float* out = (float*)d_out;

    char* ws = (char*)d_ws;
    unsigned short* featb = (unsigned short*)ws; ws += (size_t)M_ * HD_ * 2;  // 51.2 MB
    float* el      = (float*)ws;  ws += (size_t)M_ * H_ * 4;    // 3.2 MB
    float* er      = (float*)ws;  ws += (size_t)M_ * H_ * 4;
    int*   counts  = (int*)ws;    ws += (size_t)N_ * 4;
    int*   offsets = (int*)ws;    ws += (size_t)(N_ + 1) * 4;
    int*   cursor  = (int*)ws;    ws += (size_t)N_ * 4;
    int*   srcs    = (int*)ws;    ws += (size_t)E_ * 4;         // 3.2 MB
    float* chsum   = (float*)ws;  ws += 256 * 4;
    float* ss      = (float*)ws;  ws += 256 * 4;

    hipMemsetAsync(counts, 0, (size_t)N_ * 4, stream);
    hipMemsetAsync(chsum, 0, 256 * 4, stream);

    gemm_kernel<<<M_ / 64, 256, 0, stream>>>(xx, W, featb);
    elr_kernel<<<4096, 256, 0, stream>>>(featb, al, ar, el, er);
    hist_kernel<<<2048, 256, 0, stream>>>(dst, counts);
    scan_kernel<<<1, 1024, 0, stream>>>(counts, offsets, cursor);
    scatter_kernel<<<2048, 256, 0, stream>>>(src, dst, cursor, srcs);
    aggregate_kernel<<<M_, 128, 0, stream>>>(offsets, srcs, el, er, featb, out);
    stats_kernel<<<2048, 256, 0, stream>>>(out, chsum);
    params_kernel<<<1, 128, 0, stream>>>(chsum, gamma, beta, ss);
    norm_kernel<<<4096, 256, 0, stream>>>(out, ss);
}

// Round 4
// 814.578 us; speedup vs baseline: 1.3070x; 1.3070x over previous
//
#include <hip/hip_runtime.h>
#include <math.h>

#define B_ 4
#define N_ 50000
#define E_ 800000
#define IN_ 128
#define H_ 4
#define D_ 32
#define HD_ 128
#define M_ (B_*N_)   // 200000 rows total
#define GR_ 32       // gemm rows per block

constexpr float GAT_SLOPE = 0.2f;
constexpr float ACT_SLOPE = 0.01f;
constexpr float BN_EPS = 1e-5f;

__device__ __forceinline__ unsigned short f2bf(float x) {
    unsigned u = __float_as_uint(x);
    unsigned r = (u + 0x7FFFu + ((u >> 16) & 1u)) >> 16;
    return (unsigned short)r;
}
__device__ __forceinline__ float bf2f(unsigned short h) {
    return __uint_as_float(((unsigned)h) << 16);
}

// ---- GEMM + fused el/er.
// 32 rows/block, 256 threads, LDS = 64KB(W) + 16KB(X) = 80KB -> 2 blocks/CU.
// X staged row-major: K-loop reads are lane-broadcasts (conflict-free).
__global__ __launch_bounds__(256) void gemm_kernel(const float* __restrict__ xx,
                                                   const float* __restrict__ W,
                                                   const float* __restrict__ al,
                                                   const float* __restrict__ ar,
                                                   unsigned short* __restrict__ featb,
                                                   float* __restrict__ el,
                                                   float* __restrict__ er) {
    __shared__ float Ws[IN_ * HD_];   // 64 KB, [k][c]
    __shared__ float Xs[GR_][IN_];    // 16 KB, row-major
    const int tid = threadIdx.x;
    const long row0 = (long)blockIdx.x * GR_;

    for (int i = tid; i < IN_ * HD_ / 4; i += 256)
        ((float4*)Ws)[i] = ((const float4*)W)[i];
    for (int i = tid; i < GR_ * IN_ / 4; i += 256)
        ((float4*)Xs)[i] = ((const float4*)(xx + row0 * IN_))[i];
    __syncthreads();

    const int cl = tid & 31;          // columns 4cl..4cl+3
    const int r0 = (tid >> 5) * 4;    // 4 rows per thread
    float acc[4][4] = {};
#pragma unroll 4
    for (int k = 0; k < IN_; k += 4) {
        float4 w0 = *(const float4*)&Ws[(k + 0) * HD_ + 4 * cl];
        float4 w1 = *(const float4*)&Ws[(k + 1) * HD_ + 4 * cl];
        float4 w2 = *(const float4*)&Ws[(k + 2) * HD_ + 4 * cl];
        float4 w3 = *(const float4*)&Ws[(k + 3) * HD_ + 4 * cl];
#pragma unroll
        for (int i = 0; i < 4; ++i) {
            float4 xv = *(const float4*)&Xs[r0 + i][k];
            acc[i][0] = fmaf(xv.x, w0.x, acc[i][0]);
            acc[i][1] = fmaf(xv.x, w0.y, acc[i][1]);
            acc[i][2] = fmaf(xv.x, w0.z, acc[i][2]);
            acc[i][3] = fmaf(xv.x, w0.w, acc[i][3]);
            acc[i][0] = fmaf(xv.y, w1.x, acc[i][0]);
            acc[i][1] = fmaf(xv.y, w1.y, acc[i][1]);
            acc[i][2] = fmaf(xv.y, w1.z, acc[i][2]);
            acc[i][3] = fmaf(xv.y, w1.w, acc[i][3]);
            acc[i][0] = fmaf(xv.z, w2.x, acc[i][0]);
            acc[i][1] = fmaf(xv.z, w2.y, acc[i][1]);
            acc[i][2] = fmaf(xv.z, w2.z, acc[i][2]);
            acc[i][3] = fmaf(xv.z, w2.w, acc[i][3]);
            acc[i][0] = fmaf(xv.w, w3.x, acc[i][0]);
            acc[i][1] = fmaf(xv.w, w3.y, acc[i][1]);
            acc[i][2] = fmaf(xv.w, w3.z, acc[i][2]);
            acc[i][3] = fmaf(xv.w, w3.w, acc[i][3]);
        }
    }

    const float4 alv = *(const float4*)&al[4 * cl];
    const float4 arv = *(const float4*)&ar[4 * cl];
#pragma unroll
    for (int i = 0; i < 4; ++i) {
        long r = row0 + r0 + i;
        ushort4 pv;
        pv.x = f2bf(acc[i][0]); pv.y = f2bf(acc[i][1]);
        pv.z = f2bf(acc[i][2]); pv.w = f2bf(acc[i][3]);
        *(ushort4*)&featb[r * HD_ + 4 * cl] = pv;
        // fused el/er: reduce channels of each head (8 consecutive cl-lanes)
        float pl = acc[i][0] * alv.x + acc[i][1] * alv.y + acc[i][2] * alv.z + acc[i][3] * alv.w;
        float pr = acc[i][0] * arv.x + acc[i][1] * arv.y + acc[i][2] * arv.z + acc[i][3] * arv.w;
#pragma unroll
        for (int o = 4; o; o >>= 1) {
            pl += __shfl_xor(pl, o, 64);
            pr += __shfl_xor(pr, o, 64);
        }
        if ((cl & 7) == 0) {
            int h = cl >> 3;
            el[r * H_ + h] = pl;
            er[r * H_ + h] = pr;
        }
    }
}

// ---- CSR build step 1: in-degree histogram over dst ----
__global__ __launch_bounds__(256) void hist_kernel(const int* __restrict__ dst,
                                                   int* __restrict__ counts) {
    for (int e = blockIdx.x * 256 + threadIdx.x; e < E_; e += gridDim.x * 256)
        atomicAdd(&counts[dst[e]], 1);
}

// ---- CSR build step 2: exclusive scan of counts -> offsets (+cursor copy) ----
__global__ __launch_bounds__(1024) void scan_kernel(const int* __restrict__ counts,
                                                    int* __restrict__ offsets,
                                                    int* __restrict__ cursor) {
    __shared__ int part[1024];
    const int tid = threadIdx.x;
    const int CH = (N_ + 1023) / 1024;   // 49
    const int base = tid * CH;
    int s = 0;
    for (int i = 0; i < CH; ++i) {
        int idx = base + i;
        if (idx < N_) s += counts[idx];
    }
    part[tid] = s;
    __syncthreads();
    for (int off = 1; off < 1024; off <<= 1) {
        int v = (tid >= off) ? part[tid - off] : 0;
        __syncthreads();
        part[tid] += v;
        __syncthreads();
    }
    int run = (tid == 0) ? 0 : part[tid - 1];
    for (int i = 0; i < CH; ++i) {
        int idx = base + i;
        if (idx < N_) {
            offsets[idx] = run;
            cursor[idx] = run;
            run += counts[idx];
        }
    }
    if (tid == 0) offsets[N_] = part[1023];   // == E_
}

// ---- CSR build step 3: scatter src ids into dst-sorted order ----
__global__ __launch_bounds__(256) void scatter_kernel(const int* __restrict__ src,
                                                      const int* __restrict__ dst,
                                                      int* __restrict__ cursor,
                                                      int* __restrict__ srcs) {
    for (int e = blockIdx.x * 256 + threadIdx.x; e < E_; e += gridDim.x * 256) {
        int pos = atomicAdd(&cursor[dst[e]], 1);
        srcs[pos] = src[e];
    }
}

// ---- per-(b,node) softmax + aggregation.
// Per 32-edge tile: each thread computes w for its own (edge,head) -> LDS;
// consume loop reads LDS broadcasts + 4-unrolled independent feat gathers.
__global__ __launch_bounds__(128) void aggregate_kernel(const int* __restrict__ offsets,
                                                        const int* __restrict__ srcs,
                                                        const float* __restrict__ el,
                                                        const float* __restrict__ er,
                                                        const unsigned short* __restrict__ featb,
                                                        float* __restrict__ out) {
    __shared__ int   s_idx[32];
    __shared__ float s_w[H_][32];
    const int t = threadIdx.x;       // channel 0..127
    const int h = t >> 5;            // head
    const int lane = t & 31;
    const long bn = blockIdx.x;      // b*N + n
    const int b = (int)(bn / N_);
    const int n = (int)(bn % N_);
    const long bbase = (long)b * N_;
    const int beg = offsets[n], end = offsets[n + 1];

    const float ern = er[(bbase + n) * H_ + h];
    const unsigned short* __restrict__ fb = featb + bbase * HD_ + t;

    float acc = 0.f, denom = 0.f;
    for (int c0 = beg; c0 < end; c0 += 32) {
        const int cnt = min(32, end - c0);
        int sj = 0;
        float w = 0.f;
        if (lane < cnt) {
            sj = srcs[c0 + lane];
            float ev = el[(bbase + sj) * H_ + h] + ern;
            ev = ev >= 0.f ? ev : GAT_SLOPE * ev;
            w = __expf(ev);   // no max-shift: scores O(+-6), alpha shift-invariant
        }
        __syncthreads();
        s_w[h][lane] = w;
        if (h == 0) s_idx[lane] = sj;
        __syncthreads();
        denom += w;
        int j = 0;
        for (; j + 3 < cnt; j += 4) {
            int s0 = s_idx[j], s1 = s_idx[j + 1], s2 = s_idx[j + 2], s3 = s_idx[j + 3];
            float w0 = s_w[h][j], w1 = s_w[h][j + 1], w2 = s_w[h][j + 2], w3 = s_w[h][j + 3];
            float f0 = bf2f(fb[(long)s0 * HD_]);
            float f1 = bf2f(fb[(long)s1 * HD_]);
            float f2 = bf2f(fb[(long)s2 * HD_]);
            float f3 = bf2f(fb[(long)s3 * HD_]);
            acc = fmaf(w0, f0, acc);
            acc = fmaf(w1, f1, acc);
            acc = fmaf(w2, f2, acc);
            acc = fmaf(w3, f3, acc);
        }
        for (; j < cnt; ++j)
            acc = fmaf(s_w[h][j], bf2f(fb[(long)s_idx[j] * HD_]), acc);
    }
#pragma unroll
    for (int o = 16; o; o >>= 1) denom += __shfl_xor(denom, o, 32);
    out[bn * HD_ + t] = acc / fmaxf(denom, 1e-9f);
}

// ---- per-channel sum/sumsq for BN (read-only) ----
__global__ __launch_bounds__(256) void stats_kernel(const float* __restrict__ out,
                                                    float* __restrict__ chsum) {
    const int tid = threadIdx.x;
    const int c = tid & 127;
    const int half = tid >> 7;
    float s = 0.f, s2 = 0.f;
    for (long rp = blockIdx.x; rp < M_ / 2; rp += gridDim.x) {
        long row = rp * 2 + half;
        float v = out[row * HD_ + c];
        s += v;
        s2 += v * v;
    }
    __shared__ float red[512];
    red[tid] = s; red[256 + tid] = s2;
    __syncthreads();
    if (tid < 128) {
        s = red[tid] + red[tid + 128];
        s2 = red[256 + tid] + red[256 + tid + 128];
        atomicAdd(&chsum[c], s);
        atomicAdd(&chsum[128 + c], s2);
    }
}

// ---- BN params: scale/shift per channel ----
__global__ void params_kernel(const float* __restrict__ chsum,
                              const float* __restrict__ gamma,
                              const float* __restrict__ beta,
                              float* __restrict__ ss) {
    int c = threadIdx.x;  // 128 threads
    float mean = chsum[c] / (float)M_;
    float var = chsum[128 + c] / (float)M_ - mean * mean;
    float rstd = rsqrtf(var + BN_EPS);
    float sc = rstd * gamma[c];
    ss[c] = sc;
    ss[128 + c] = beta[c] - mean * sc;
}

// ---- normalize + final leaky relu, in place on d_out ----
__global__ __launch_bounds__(256) void norm_kernel(float* __restrict__ out,
                                                   const float* __restrict__ ss) {
    __shared__ float s_sc[128], s_sh[128];
    if (threadIdx.x < 128) {
        s_sc[threadIdx.x] = ss[threadIdx.x];
        s_sh[threadIdx.x] = ss[128 + threadIdx.x];
    }
    __syncthreads();
    const long total4 = (long)M_ * HD_ / 4;
    for (long i = (long)blockIdx.x * 256 + threadIdx.x; i < total4;
         i += (long)gridDim.x * 256) {
        float4 v = ((float4*)out)[i];
        int c = (int)((i & 31) << 2);   // (i*4) % 128
        float4 r;
        r.x = v.x * s_sc[c + 0] + s_sh[c + 0];
        r.y = v.y * s_sc[c + 1] + s_sh[c + 1];
        r.z = v.z * s_sc[c + 2] + s_sh[c + 2];
        r.w = v.w * s_sc[c + 3] + s_sh[c + 3];
        r.x = r.x >= 0.f ? r.x : ACT_SLOPE * r.x;
        r.y = r.y >= 0.f ? r.y : ACT_SLOPE * r.y;
        r.z = r.z >= 0.f ? r.z : ACT_SLOPE * r.z;
        r.w = r.w >= 0.f ? r.w : ACT_SLOPE * r.w;
        ((float4*)out)[i] = r;
    }
}

extern "C" void kernel_launch(void* const* d_in, const int* in_sizes, int n_in,
                              void* d_out, int out_size, void* d_ws, size_t ws_size,
                              hipStream_t stream) {
    const float* xx    = (const float*)d_in[0];
    const float* W     = (const float*)d_in[1];
    const float* al    = (const float*)d_in[2];
    const float* ar    = (const float*)d_in[3];
    const float* gamma = (const float*)d_in[4];
    const float* beta  = (const float*)d_in[5];
    const int*   src   = (const int*)d_in[6];
    const int*   dst   = (const int*)d_in[7];
    float* out = (float*)d_out;

    char* ws = (char*)d_ws;
    unsigned short* featb = (unsigned short*)ws; ws += (size_t)M_ * HD_ * 2;  // 51.2 MB
    float* el      = (float*)ws;  ws += (size_t)M_ * H_ * 4;    // 3.2 MB
    float* er      = (float*)ws;  ws += (size_t)M_ * H_ * 4;
    int*   counts  = (int*)ws;    ws += (size_t)N_ * 4;
    int*   offsets = (int*)ws;    ws += (size_t)(N_ + 1) * 4;
    int*   cursor  = (int*)ws;    ws += (size_t)N_ * 4;
    int*   srcs    = (int*)ws;    ws += (size_t)E_ * 4;         // 3.2 MB
    float* chsum   = (float*)ws;  ws += 256 * 4;
    float* ss      = (float*)ws;  ws += 256 * 4;

    hipMemsetAsync(counts, 0, (size_t)N_ * 4, stream);
    hipMemsetAsync(chsum, 0, 256 * 4, stream);

    gemm_kernel<<<M_ / GR_, 256, 0, stream>>>(xx, W, al, ar, featb, el, er);
    hist_kernel<<<2048, 256, 0, stream>>>(dst, counts);
    scan_kernel<<<1, 1024, 0, stream>>>(counts, offsets, cursor);
    scatter_kernel<<<2048, 256, 0, stream>>>(src, dst, cursor, srcs);
    aggregate_kernel<<<M_, 128, 0, stream>>>(offsets, srcs, el, er, featb, out);
    stats_kernel<<<2048, 256, 0, stream>>>(out, chsum);
    params_kernel<<<1, 128, 0, stream>>>(chsum, gamma, beta, ss);
    norm_kernel<<<4096, 256, 0, stream>>>(out, ss);
}

// Round 6
// 704.809 us; speedup vs baseline: 1.5106x; 1.1557x over previous
//
#include <hip/hip_runtime.h>
#include <math.h>

#define B_ 4
#define N_ 50000
#define E_ 800000
#define IN_ 128
#define H_ 4
#define D_ 32
#define HD_ 128
#define M_ (B_*N_)   // 200000 rows total
#define GR_ 32       // gemm rows per tile
#define GEMM_BLOCKS 512

constexpr float GAT_SLOPE = 0.2f;
constexpr float ACT_SLOPE = 0.01f;
constexpr float BN_EPS = 1e-5f;

__device__ __forceinline__ unsigned short f2bf(float x) {
    unsigned u = __float_as_uint(x);
    unsigned r = (u + 0x7FFFu + ((u >> 16) & 1u)) >> 16;
    return (unsigned short)r;
}
__device__ __forceinline__ float bflo(unsigned u) {   // channel 2t (low ushort)
    return __uint_as_float(u << 16);
}
__device__ __forceinline__ float bfhi(unsigned u) {   // channel 2t+1 (high ushort)
    return __uint_as_float(u & 0xFFFF0000u);
}

// ---- Persistent GEMM + fused el/er.
// 512 blocks grid-stride over 6250 row-tiles; W loaded to LDS ONCE per block
// (W refetch 400MB -> 32MB). LDS = 64KB(W)+16KB(X) = 80KB -> 2 blocks/CU.
__global__ __launch_bounds__(256) void gemm_kernel(const float* __restrict__ xx,
                                                   const float* __restrict__ W,
                                                   const float* __restrict__ al,
                                                   const float* __restrict__ ar,
                                                   unsigned short* __restrict__ featb,
                                                   float* __restrict__ el,
                                                   float* __restrict__ er) {
    __shared__ float Ws[IN_ * HD_];   // 64 KB, [k][c]
    __shared__ float Xs[GR_][IN_];    // 16 KB, row-major
    const int tid = threadIdx.x;
    const int cl = tid & 31;          // columns 4cl..4cl+3
    const int r0 = (tid >> 5) * 4;    // 4 rows per thread

    for (int i = tid; i < IN_ * HD_ / 4; i += 256)
        ((float4*)Ws)[i] = ((const float4*)W)[i];

    const float4 alv = *(const float4*)&al[4 * cl];
    const float4 arv = *(const float4*)&ar[4 * cl];

    for (int tt = blockIdx.x; tt < M_ / GR_; tt += GEMM_BLOCKS) {
        const long row0 = (long)tt * GR_;
        __syncthreads();   // protect Xs (prev readers) / cover Ws on first iter
        for (int i = tid; i < GR_ * IN_ / 4; i += 256)
            ((float4*)Xs)[i] = ((const float4*)(xx + row0 * IN_))[i];
        __syncthreads();

        float acc[4][4] = {};
#pragma unroll 4
        for (int k = 0; k < IN_; k += 4) {
            float4 w0 = *(const float4*)&Ws[(k + 0) * HD_ + 4 * cl];
            float4 w1 = *(const float4*)&Ws[(k + 1) * HD_ + 4 * cl];
            float4 w2 = *(const float4*)&Ws[(k + 2) * HD_ + 4 * cl];
            float4 w3 = *(const float4*)&Ws[(k + 3) * HD_ + 4 * cl];
#pragma unroll
            for (int i = 0; i < 4; ++i) {
                float4 xv = *(const float4*)&Xs[r0 + i][k];
                acc[i][0] = fmaf(xv.x, w0.x, acc[i][0]);
                acc[i][1] = fmaf(xv.x, w0.y, acc[i][1]);
                acc[i][2] = fmaf(xv.x, w0.z, acc[i][2]);
                acc[i][3] = fmaf(xv.x, w0.w, acc[i][3]);
                acc[i][0] = fmaf(xv.y, w1.x, acc[i][0]);
                acc[i][1] = fmaf(xv.y, w1.y, acc[i][1]);
                acc[i][2] = fmaf(xv.y, w1.z, acc[i][2]);
                acc[i][3] = fmaf(xv.y, w1.w, acc[i][3]);
                acc[i][0] = fmaf(xv.z, w2.x, acc[i][0]);
                acc[i][1] = fmaf(xv.z, w2.y, acc[i][1]);
                acc[i][2] = fmaf(xv.z, w2.z, acc[i][2]);
                acc[i][3] = fmaf(xv.z, w2.w, acc[i][3]);
                acc[i][0] = fmaf(xv.w, w3.x, acc[i][0]);
                acc[i][1] = fmaf(xv.w, w3.y, acc[i][1]);
                acc[i][2] = fmaf(xv.w, w3.z, acc[i][2]);
                acc[i][3] = fmaf(xv.w, w3.w, acc[i][3]);
            }
        }

#pragma unroll
        for (int i = 0; i < 4; ++i) {
            long r = row0 + r0 + i;
            ushort4 pv;
            pv.x = f2bf(acc[i][0]); pv.y = f2bf(acc[i][1]);
            pv.z = f2bf(acc[i][2]); pv.w = f2bf(acc[i][3]);
            *(ushort4*)&featb[r * HD_ + 4 * cl] = pv;
            float pl = acc[i][0] * alv.x + acc[i][1] * alv.y + acc[i][2] * alv.z + acc[i][3] * alv.w;
            float pr = acc[i][0] * arv.x + acc[i][1] * arv.y + acc[i][2] * arv.z + acc[i][3] * arv.w;
#pragma unroll
            for (int o = 4; o; o >>= 1) {
                pl += __shfl_xor(pl, o, 64);
                pr += __shfl_xor(pr, o, 64);
            }
            if ((cl & 7) == 0) {
                int h = cl >> 3;
                el[r * H_ + h] = pl;
                er[r * H_ + h] = pr;
            }
        }
    }
}

// ---- CSR build step 1: in-degree histogram over dst ----
__global__ __launch_bounds__(256) void hist_kernel(const int* __restrict__ dst,
                                                   int* __restrict__ counts) {
    for (int e = blockIdx.x * 256 + threadIdx.x; e < E_; e += gridDim.x * 256)
        atomicAdd(&counts[dst[e]], 1);
}

// ---- CSR build step 2: exclusive scan of counts -> offsets (+cursor copy) ----
__global__ __launch_bounds__(1024) void scan_kernel(const int* __restrict__ counts,
                                                    int* __restrict__ offsets,
                                                    int* __restrict__ cursor) {
    __shared__ int part[1024];
    const int tid = threadIdx.x;
    const int CH = (N_ + 1023) / 1024;   // 49
    const int base = tid * CH;
    int s = 0;
    for (int i = 0; i < CH; ++i) {
        int idx = base + i;
        if (idx < N_) s += counts[idx];
    }
    part[tid] = s;
    __syncthreads();
    for (int off = 1; off < 1024; off <<= 1) {
        int v = (tid >= off) ? part[tid - off] : 0;
        __syncthreads();
        part[tid] += v;
        __syncthreads();
    }
    int run = (tid == 0) ? 0 : part[tid - 1];
    for (int i = 0; i < CH; ++i) {
        int idx = base + i;
        if (idx < N_) {
            offsets[idx] = run;
            cursor[idx] = run;
            run += counts[idx];
        }
    }
    if (tid == 0) offsets[N_] = part[1023];   // == E_
}

// ---- CSR build step 3: scatter src ids into dst-sorted order ----
__global__ __launch_bounds__(256) void scatter_kernel(const int* __restrict__ src,
                                                      const int* __restrict__ dst,
                                                      int* __restrict__ cursor,
                                                      int* __restrict__ srcs) {
    for (int e = blockIdx.x * 256 + threadIdx.x; e < E_; e += gridDim.x * 256) {
        int pos = atomicAdd(&cursor[dst[e]], 1);
        srcs[pos] = src[e];
    }
}

// ---- per-(b,node) softmax + aggregation: ONE WAVE per (b,n).
// Lane t owns channels {2t, 2t+1} (head h = t>>4): gathers are dword loads.
// Per 16-edge tile, lane l computes w for (edge l&15, head l>>4); w and the
// precomputed byte offset are shared via shfl (no LDS, no barriers).
// blockIdx->(b,n) swizzled so XCD k serves only batch k/2 (L2 affinity).
__global__ __launch_bounds__(64) void aggregate_kernel(const int* __restrict__ offsets,
                                                       const int* __restrict__ srcs,
                                                       const float* __restrict__ el,
                                                       const float* __restrict__ er,
                                                       const unsigned short* __restrict__ featb,
                                                       float* __restrict__ out) {
    const int t = threadIdx.x;        // 0..63
    const int h = t >> 4;             // head of channels 2t,2t+1
    const int hb = t & 48;            // head-group base lane
    const int t4 = 4 * t;             // byte offset of dword within feat row
    const unsigned g = blockIdx.x;    // 200000 blocks, %8==0
    const int xcd = (int)(g & 7u);
    const int b = xcd >> 1;           // 2 XCDs per batch
    const int n = (int)((g >> 3) * 2 + (xcd & 1));
    const long bbase = (long)b * N_;
    const int beg = offsets[n], end = offsets[n + 1];

    const float ern = er[(bbase + n) * H_ + h];
    const char* fbase = (const char*)(featb + bbase * HD_);
    const int j16 = t & 15;

    float acc0 = 0.f, acc1 = 0.f, dsum = 0.f;
    for (int c0 = beg; c0 < end; c0 += 16) {
        const int cnt = min(16, end - c0);
        float w = 0.f;
        int off = 0;
        if (j16 < cnt) {
            int s = srcs[c0 + j16];
            off = s << 8;   // s * 256 bytes (128 bf16 per row)
            float ev = el[(bbase + s) * H_ + h] + ern;
            ev = ev >= 0.f ? ev : GAT_SLOPE * ev;
            w = __expf(ev);   // no max-shift: scores O(+-6), alpha shift-invariant
        }
        dsum += w;
        int j = 0;
        for (; j + 3 < cnt; j += 4) {
            int o0 = __shfl(off, j);
            int o1 = __shfl(off, j + 1);
            int o2 = __shfl(off, j + 2);
            int o3 = __shfl(off, j + 3);
            float w0 = __shfl(w, hb | j);
            float w1 = __shfl(w, hb | (j + 1));
            float w2 = __shfl(w, hb | (j + 2));
            float w3 = __shfl(w, hb | (j + 3));
            unsigned u0 = *(const unsigned*)(fbase + o0 + t4);
            unsigned u1 = *(const unsigned*)(fbase + o1 + t4);
            unsigned u2 = *(const unsigned*)(fbase + o2 + t4);
            unsigned u3 = *(const unsigned*)(fbase + o3 + t4);
            acc0 = fmaf(w0, bflo(u0), acc0); acc1 = fmaf(w0, bfhi(u0), acc1);
            acc0 = fmaf(w1, bflo(u1), acc0); acc1 = fmaf(w1, bfhi(u1), acc1);
            acc0 = fmaf(w2, bflo(u2), acc0); acc1 = fmaf(w2, bfhi(u2), acc1);
            acc0 = fmaf(w3, bflo(u3), acc0); acc1 = fmaf(w3, bfhi(u3), acc1);
        }
        for (; j < cnt; ++j) {
            int o0 = __shfl(off, j);
            float w0 = __shfl(w, hb | j);
            unsigned u0 = *(const unsigned*)(fbase + o0 + t4);
            acc0 = fmaf(w0, bflo(u0), acc0);
            acc1 = fmaf(w0, bfhi(u0), acc1);
        }
    }
    // reduce dsum within each 16-lane head group
#pragma unroll
    for (int o = 8; o; o >>= 1) dsum += __shfl_xor(dsum, o, 64);
    const float inv = 1.0f / fmaxf(dsum, 1e-9f);
    float2 res = make_float2(acc0 * inv, acc1 * inv);
    *(float2*)&out[((bbase + n) * HD_) + 2 * t] = res;
}

// ---- per-channel sum/sumsq for BN (read-only) ----
__global__ __launch_bounds__(256) void stats_kernel(const float* __restrict__ out,
                                                    float* __restrict__ chsum) {
    const int tid = threadIdx.x;
    const int c = tid & 127;
    const int half = tid >> 7;
    float s = 0.f, s2 = 0.f;
    for (long rp = blockIdx.x; rp < M_ / 2; rp += gridDim.x) {
        long row = rp * 2 + half;
        float v = out[row * HD_ + c];
        s += v;
        s2 += v * v;
    }
    __shared__ float red[512];
    red[tid] = s; red[256 + tid] = s2;
    __syncthreads();
    if (tid < 128) {
        s = red[tid] + red[tid + 128];
        s2 = red[256 + tid] + red[256 + tid + 128];
        atomicAdd(&chsum[c], s);
        atomicAdd(&chsum[128 + c], s2);
    }
}

// ---- BN params: scale/shift per channel ----
__global__ void params_kernel(const float* __restrict__ chsum,
                              const float* __restrict__ gamma,
                              const float* __restrict__ beta,
                              float* __restrict__ ss) {
    int c = threadIdx.x;  // 128 threads
    float mean = chsum[c] / (float)M_;
    float var = chsum[128 + c] / (float)M_ - mean * mean;
    float rstd = rsqrtf(var + BN_EPS);
    float sc = rstd * gamma[c];
    ss[c] = sc;
    ss[128 + c] = beta[c] - mean * sc;
}

// ---- normalize + final leaky relu, in place on d_out ----
__global__ __launch_bounds__(256) void norm_kernel(float* __restrict__ out,
                                                   const float* __restrict__ ss) {
    __shared__ float s_sc[128], s_sh[128];
    if (threadIdx.x < 128) {
        s_sc[threadIdx.x] = ss[threadIdx.x];
        s_sh[threadIdx.x] = ss[128 + threadIdx.x];
    }
    __syncthreads();
    const long total4 = (long)M_ * HD_ / 4;
    for (long i = (long)blockIdx.x * 256 + threadIdx.x; i < total4;
         i += (long)gridDim.x * 256) {
        float4 v = ((float4*)out)[i];
        int c = (int)((i & 31) << 2);   // (i*4) % 128
        float4 r;
        r.x = v.x * s_sc[c + 0] + s_sh[c + 0];
        r.y = v.y * s_sc[c + 1] + s_sh[c + 1];
        r.z = v.z * s_sc[c + 2] + s_sh[c + 2];
        r.w = v.w * s_sc[c + 3] + s_sh[c + 3];
        r.x = r.x >= 0.f ? r.x : ACT_SLOPE * r.x;
        r.y = r.y >= 0.f ? r.y : ACT_SLOPE * r.y;
        r.z = r.z >= 0.f ? r.z : ACT_SLOPE * r.z;
        r.w = r.w >= 0.f ? r.w : ACT_SLOPE * r.w;
        ((float4*)out)[i] = r;
    }
}

extern "C" void kernel_launch(void* const* d_in, const int* in_sizes, int n_in,
                              void* d_out, int out_size, void* d_ws, size_t ws_size,
                              hipStream_t stream) {
    const float* xx    = (const float*)d_in[0];
    const float* W     = (const float*)d_in[1];
    const float* al    = (const float*)d_in[2];
    const float* ar    = (const float*)d_in[3];
    const float* gamma = (const float*)d_in[4];
    const float* beta  = (const float*)d_in[5];
    const int*   src   = (const int*)d_in[6];
    const int*   dst   = (const int*)d_in[7];
    float* out = (float*)d_out;

    char* ws = (char*)d_ws;
    unsigned short* featb = (unsigned short*)ws; ws += (size_t)M_ * HD_ * 2;  // 51.2 MB
    float* el      = (float*)ws;  ws += (size_t)M_ * H_ * 4;    // 3.2 MB
    float* er      = (float*)ws;  ws += (size_t)M_ * H_ * 4;
    int*   counts  = (int*)ws;    ws += (size_t)N_ * 4;
    int*   offsets = (int*)ws;    ws += (size_t)(N_ + 1) * 4;
    int*   cursor  = (int*)ws;    ws += (size_t)N_ * 4;
    int*   srcs    = (int*)ws;    ws += (size_t)E_ * 4;         // 3.2 MB
    float* chsum   = (float*)ws;  ws += 256 * 4;
    float* ss      = (float*)ws;  ws += 256 * 4;

    hipMemsetAsync(counts, 0, (size_t)N_ * 4, stream);
    hipMemsetAsync(chsum, 0, 256 * 4, stream);

    gemm_kernel<<<GEMM_BLOCKS, 256, 0, stream>>>(xx, W, al, ar, featb, el, er);
    hist_kernel<<<2048, 256, 0, stream>>>(dst, counts);
    scan_kernel<<<1, 1024, 0, stream>>>(counts, offsets, cursor);
    scatter_kernel<<<2048, 256, 0, stream>>>(src, dst, cursor, srcs);
    aggregate_kernel<<<M_, 64, 0, stream>>>(offsets, srcs, el, er, featb, out);
    stats_kernel<<<2048, 256, 0, stream>>>(out, chsum);
    params_kernel<<<1, 128, 0, stream>>>(chsum, gamma, beta, ss);
    norm_kernel<<<4096, 256, 0, stream>>>(out, ss);
}